// Round 1
// baseline (149.414 us; speedup 1.0000x reference)
//
#include <hip/hip_runtime.h>
#include <math.h>

#define NPTS_C 100
#define EPS_C 1e-8

__device__ __forceinline__ float wave_reduce_sum(float v) {
#pragma unroll
    for (int m = 1; m < 64; m <<= 1)
        v += __shfl_xor(v, m, 64);
    return v;
}

// One wave per row. Block = 256 threads = 4 waves.
// LDS: log(grid), log1p(-grid) tables (550 pts for K=10) + Wa/Wb staged.
__global__ __launch_bounds__(256, 4) void ub_kernel(
    const float* __restrict__ x, const float* __restrict__ Wa,
    const float* __restrict__ ba, const float* __restrict__ Wb,
    const float* __restrict__ bb, float* __restrict__ out,
    int B, int C, int K)
{
    __shared__ __align__(16) float s_lg[600];
    __shared__ __align__(16) float s_l1g[600];
    __shared__ __align__(16) float s_w[1024];  // [0..C): Wa, [C..2C): Wb

    const int tid = threadIdx.x;

    // Stage weights (C <= 512 here).
    for (int c = tid; c < C; c += blockDim.x) {
        s_w[c]     = Wa[c];
        s_w[C + c] = Wb[c];
    }

    // Build grid log-tables once per block (row-invariant).
    {
        int base = 0;
        for (int i = 1; i <= K; ++i) {
            const int n = (int)((double)NPTS_C * ((double)i / (double)K)); // matches int(NPTS*(i/K))
            const double start = EPS_C;
            const double stop  = (double)i / (double)K - EPS_C;
            const double step  = (n > 1) ? (stop - start) / (double)(n - 1) : 0.0;
            for (int j = tid; j < n; j += blockDim.x) {
                float g = (j == n - 1) ? (float)stop : (float)(start + step * (double)j);
                s_lg[base + j]  = logf(g);
                s_l1g[base + j] = log1pf(-g);
            }
            base += n;
        }
    }
    __syncthreads();

    const float ba0 = ba[0], bb0 = bb[0];
    const int wave = tid >> 6;
    const int lane = tid & 63;
    const int wavesPerBlock = blockDim.x >> 6;
    const int waveId = blockIdx.x * wavesPerBlock + wave;
    const int nWaves = gridDim.x * wavesPerBlock;

    for (int row = waveId; row < B; row += nWaves) {
        const float* xr = x + (size_t)row * C;

        // --- two dots over the row (coalesced float4, weights from LDS) ---
        float da = 0.f, db = 0.f;
        for (int c0 = 0; c0 < C; c0 += 256) {
            const float4 xv = *reinterpret_cast<const float4*>(xr + c0 + 4 * lane);
            const float4 wa = *reinterpret_cast<const float4*>(&s_w[c0 + 4 * lane]);
            const float4 wb = *reinterpret_cast<const float4*>(&s_w[C + c0 + 4 * lane]);
            da += xv.x * wa.x + xv.y * wa.y + xv.z * wa.z + xv.w * wa.w;
            db += xv.x * wb.x + xv.y * wb.y + xv.z * wb.z + xv.w * wb.w;
        }
        da = wave_reduce_sum(da) + ba0;
        db = wave_reduce_sum(db) + bb0;

        // softplus(x) = max(x,0) + log1p(exp(-|x|)); alpha/beta = clip(1+sp, 1, 100)
        const float sa = fmaxf(da, 0.f) + log1pf(expf(-fabsf(da)));
        const float sb = fmaxf(db, 0.f) + log1pf(expf(-fabsf(db)));
        const float alpha = fminf(fmaxf(1.f + sa, 1.f), 100.f);
        const float beta  = fminf(fmaxf(1.f + sb, 1.f), 100.f);
        const float log_norm = lgammaf(alpha) + lgammaf(beta) - lgammaf(alpha + beta);
        const float am1 = alpha - 1.f, bm1 = beta - 1.f;

        // --- quadrature: cdf_i = sum_j exp((a-1)lg + (b-1)l1g - log_norm) ---
        // dx and any uniform scale cancel in the normalization; sum(probs) = cdf_K.
        float cdf_prev = 0.f, myp = 0.f;
        int base = 0;
        for (int i = 1; i <= K; ++i) {
            const int n = (int)((double)NPTS_C * ((double)i / (double)K));
            float s = 0.f;
            for (int p = lane; p < n; p += 64) {
                const float lp = fmaf(am1, s_lg[base + p],
                                 fmaf(bm1, s_l1g[base + p], -log_norm));
                s += expf(lp);
            }
            const float cdf = wave_reduce_sum(s);
            if (lane == i - 1) myp = cdf - cdf_prev;
            cdf_prev = cdf;
            base += n;
        }
        if (lane < K)
            out[(size_t)row * K + lane] = myp / cdf_prev;
    }
}

extern "C" void kernel_launch(void* const* d_in, const int* in_sizes, int n_in,
                              void* d_out, int out_size, void* d_ws, size_t ws_size,
                              hipStream_t stream) {
    const float* x  = (const float*)d_in[0];
    const float* Wa = (const float*)d_in[1];
    const float* ba = (const float*)d_in[2];
    const float* Wb = (const float*)d_in[3];
    const float* bb = (const float*)d_in[4];
    float* out = (float*)d_out;

    const int C = in_sizes[1];           // 512
    const int B = in_sizes[0] / C;       // 65536
    const int K = out_size / B;          // 10

    // 4 waves/block; ~8 rows per wave via grid-stride.
    int nblocks = (B + 3) / 4;
    if (nblocks > 2048) nblocks = 2048;
    ub_kernel<<<nblocks, 256, 0, stream>>>(x, Wa, ba, Wb, bb, out, B, C, K);
}

// Round 3
// 47.041 us; speedup vs baseline: 3.1763x; 3.1763x over previous
//
#include <hip/hip_runtime.h>
#include <math.h>

#define NPTS_C 100
#define EPS_C 1e-8

#if defined(__has_builtin)
# if __has_builtin(__builtin_amdgcn_exp2f)
#  define FAST_EXP2(x) __builtin_amdgcn_exp2f(x)
# else
#  define FAST_EXP2(x) exp2f(x)
# endif
#else
# define FAST_EXP2(x) exp2f(x)
#endif

__device__ __forceinline__ float wave_reduce_sum(float v) {
#pragma unroll
    for (int m = 1; m < 64; m <<= 1)
        v += __shfl_xor(v, m, 64);
    return v;
}

// ---------------- K1: GEMV — one wave per row, memory-bound ----------------
__global__ __launch_bounds__(256) void gemv_kernel(
    const float* __restrict__ x, const float* __restrict__ Wa,
    const float* __restrict__ ba, const float* __restrict__ Wb,
    const float* __restrict__ bb, float2* __restrict__ ws,
    int B, int C)
{
    const int tid  = threadIdx.x;
    const int lane = tid & 63;
    const int wave = tid >> 6;
    const int waveId = blockIdx.x * (blockDim.x >> 6) + wave;
    const int nWaves = gridDim.x * (blockDim.x >> 6);
    const float ba0 = ba[0], bb0 = bb[0];

    for (int row = waveId; row < B; row += nWaves) {
        const float* xr = x + (size_t)row * C;
        float da = 0.f, db = 0.f;
        for (int c0 = 4 * lane; c0 < C; c0 += 256) {
            const float4 xv = *reinterpret_cast<const float4*>(xr + c0);
            const float4 wa = *reinterpret_cast<const float4*>(Wa + c0);
            const float4 wb = *reinterpret_cast<const float4*>(Wb + c0);
            da += xv.x * wa.x + xv.y * wa.y + xv.z * wa.z + xv.w * wa.w;
            db += xv.x * wb.x + xv.y * wb.y + xv.z * wb.z + xv.w * wb.w;
        }
        da = wave_reduce_sum(da) + ba0;
        db = wave_reduce_sum(db) + bb0;
        if (lane == 0) ws[row] = make_float2(da, db);
    }
}

// ------------- K2: quadrature — one THREAD per row, no reductions ----------
// Tables in log2-space built from FLOAT32-ROUNDED grid values (matches the
// reference's float32 grid exactly; in particular the last point of the last
// segment rounds to 1.0f -> log2(1-g)= -inf -> exp2 -> 0, as in the ref).
// lgamma eliminated: stabilize by lp at the beta mode; any per-row constant
// cancels in probs/sum(probs).
__device__ __forceinline__ float seg_sum(const float* __restrict__ lg2,
                                         const float* __restrict__ l1g2,
                                         int base, int n,
                                         float am1, float bm1, float M2)
{
    float s0 = 0.f, s1 = 0.f;
    int p = 0;
    for (; p + 1 < n; p += 2) {
        s0 += FAST_EXP2(fmaf(am1, lg2[base + p],     fmaf(bm1, l1g2[base + p],     -M2)));
        s1 += FAST_EXP2(fmaf(am1, lg2[base + p + 1], fmaf(bm1, l1g2[base + p + 1], -M2)));
    }
    if (p < n)
        s0 += FAST_EXP2(fmaf(am1, lg2[base + p], fmaf(bm1, l1g2[base + p], -M2)));
    return s0 + s1;
}

__global__ __launch_bounds__(256) void quad_kernel(
    const float2* __restrict__ ws, float* __restrict__ out, int B, int K)
{
    __shared__ __align__(16) float s_lg2[600];
    __shared__ __align__(16) float s_l1g2[600];

    // Build row-invariant log2 tables once per block.
    {
        int base = 0;
        for (int i = 1; i <= K; ++i) {
            const int n = (int)((double)NPTS_C * ((double)i / (double)K));
            const double start = EPS_C;
            const double stop  = (double)i / (double)K - EPS_C;
            const double step  = (n > 1) ? (stop - start) / (double)(n - 1) : 0.0;
            for (int j = threadIdx.x; j < n; j += blockDim.x) {
                const double g = (j == n - 1) ? stop : start + step * (double)j;
                const float g32 = (float)g;           // <- float32 grid, as in ref
                s_lg2[base + j]  = (float)log2((double)g32);
                s_l1g2[base + j] = (float)log2(1.0 - (double)g32); // -inf at g32==1
            }
            base += n;
        }
    }
    __syncthreads();

    const int r = blockIdx.x * blockDim.x + threadIdx.x;
    if (r >= B) return;

    const float da = ws[r].x, db = ws[r].y;
    // softplus + clip (softplus > 0 always -> am1, bm1 > 0 strictly)
    const float sa = fmaxf(da, 0.f) + log1pf(expf(-fabsf(da)));
    const float sb = fmaxf(db, 0.f) + log1pf(expf(-fabsf(db)));
    const float alpha = fminf(fmaxf(1.f + sa, 1.f), 100.f);
    const float beta  = fminf(fmaxf(1.f + sb, 1.f), 100.f);
    const float am1 = alpha - 1.f, bm1 = beta - 1.f;

    // Stabilizer at the beta mode (log2 space); cancels in normalization.
    const float den = am1 + bm1;
    float m = (den > 0.f) ? am1 / den : 0.5f;
    m = fminf(fmaxf(m, 1e-6f), 1.f - 1e-6f);
    const float M2 = am1 * log2f(m) + bm1 * log2f(1.f - m);

    // total = cdf_K (telescoping sum of probs).
    int baseK = 0;
    for (int i = 1; i < K; ++i)
        baseK += (int)((double)NPTS_C * ((double)i / (double)K));
    const int nK = (int)((double)NPTS_C * 1.0);
    const float total = seg_sum(s_lg2, s_l1g2, baseK, nK, am1, bm1, M2);
    const float inv_total = 1.f / total;

    float cdf_prev = 0.f;
    int base = 0;
    float* orow = out + (size_t)r * K;
    for (int i = 1; i <= K; ++i) {
        const int n = (int)((double)NPTS_C * ((double)i / (double)K));
        const float s = seg_sum(s_lg2, s_l1g2, base, n, am1, bm1, M2);
        orow[i - 1] = (s - cdf_prev) * inv_total;
        cdf_prev = s;
        base += n;
    }
}

// ---------------- Fallback: round-1 fused kernel (passed) ------------------
__global__ __launch_bounds__(256, 4) void ub_fused_kernel(
    const float* __restrict__ x, const float* __restrict__ Wa,
    const float* __restrict__ ba, const float* __restrict__ Wb,
    const float* __restrict__ bb, float* __restrict__ out,
    int B, int C, int K)
{
    __shared__ __align__(16) float s_lg[600];
    __shared__ __align__(16) float s_l1g[600];
    __shared__ __align__(16) float s_w[1024];

    const int tid = threadIdx.x;
    for (int c = tid; c < C; c += blockDim.x) {
        s_w[c]     = Wa[c];
        s_w[C + c] = Wb[c];
    }
    {
        int base = 0;
        for (int i = 1; i <= K; ++i) {
            const int n = (int)((double)NPTS_C * ((double)i / (double)K));
            const double start = EPS_C;
            const double stop  = (double)i / (double)K - EPS_C;
            const double step  = (n > 1) ? (stop - start) / (double)(n - 1) : 0.0;
            for (int j = tid; j < n; j += blockDim.x) {
                float g = (j == n - 1) ? (float)stop : (float)(start + step * (double)j);
                s_lg[base + j]  = logf(g);
                s_l1g[base + j] = log1pf(-g);
            }
            base += n;
        }
    }
    __syncthreads();

    const float ba0 = ba[0], bb0 = bb[0];
    const int wave = tid >> 6;
    const int lane = tid & 63;
    const int wavesPerBlock = blockDim.x >> 6;
    const int waveId = blockIdx.x * wavesPerBlock + wave;
    const int nWaves = gridDim.x * wavesPerBlock;

    for (int row = waveId; row < B; row += nWaves) {
        const float* xr = x + (size_t)row * C;
        float da = 0.f, db = 0.f;
        for (int c0 = 0; c0 < C; c0 += 256) {
            const float4 xv = *reinterpret_cast<const float4*>(xr + c0 + 4 * lane);
            const float4 wa = *reinterpret_cast<const float4*>(&s_w[c0 + 4 * lane]);
            const float4 wb = *reinterpret_cast<const float4*>(&s_w[C + c0 + 4 * lane]);
            da += xv.x * wa.x + xv.y * wa.y + xv.z * wa.z + xv.w * wa.w;
            db += xv.x * wb.x + xv.y * wb.y + xv.z * wb.z + xv.w * wb.w;
        }
        da = wave_reduce_sum(da) + ba0;
        db = wave_reduce_sum(db) + bb0;

        const float sa = fmaxf(da, 0.f) + log1pf(expf(-fabsf(da)));
        const float sb = fmaxf(db, 0.f) + log1pf(expf(-fabsf(db)));
        const float alpha = fminf(fmaxf(1.f + sa, 1.f), 100.f);
        const float beta  = fminf(fmaxf(1.f + sb, 1.f), 100.f);
        const float log_norm = lgammaf(alpha) + lgammaf(beta) - lgammaf(alpha + beta);
        const float am1 = alpha - 1.f, bm1 = beta - 1.f;

        float cdf_prev = 0.f, myp = 0.f;
        int base = 0;
        for (int i = 1; i <= K; ++i) {
            const int n = (int)((double)NPTS_C * ((double)i / (double)K));
            float s = 0.f;
            for (int p = lane; p < n; p += 64) {
                const float lp = fmaf(am1, s_lg[base + p],
                                 fmaf(bm1, s_l1g[base + p], -log_norm));
                s += expf(lp);
            }
            const float cdf = wave_reduce_sum(s);
            if (lane == i - 1) myp = cdf - cdf_prev;
            cdf_prev = cdf;
            base += n;
        }
        if (lane < K)
            out[(size_t)row * K + lane] = myp / cdf_prev;
    }
}

extern "C" void kernel_launch(void* const* d_in, const int* in_sizes, int n_in,
                              void* d_out, int out_size, void* d_ws, size_t ws_size,
                              hipStream_t stream) {
    const float* x  = (const float*)d_in[0];
    const float* Wa = (const float*)d_in[1];
    const float* ba = (const float*)d_in[2];
    const float* Wb = (const float*)d_in[3];
    const float* bb = (const float*)d_in[4];
    float* out = (float*)d_out;

    const int C = in_sizes[1];           // 512
    const int B = in_sizes[0] / C;       // 65536
    const int K = out_size / B;          // 10

    int NP = 0;
    for (int i = 1; i <= K; ++i)
        NP += (int)((double)NPTS_C * ((double)i / (double)K));

    const bool fast_ok = (C % 256 == 0) && (NP <= 600) &&
                         (ws_size >= (size_t)B * sizeof(float2));

    if (fast_ok) {
        float2* ws = (float2*)d_ws;
        int nblocks = (B + 3) / 4;
        if (nblocks > 2048) nblocks = 2048;
        gemv_kernel<<<nblocks, 256, 0, stream>>>(x, Wa, ba, Wb, bb, ws, B, C);
        quad_kernel<<<(B + 255) / 256, 256, 0, stream>>>(ws, out, B, K);
    } else {
        int nblocks = (B + 3) / 4;
        if (nblocks > 2048) nblocks = 2048;
        ub_fused_kernel<<<nblocks, 256, 0, stream>>>(x, Wa, ba, Wb, bb, out, B, C, K);
    }
}

// Round 4
// 41.227 us; speedup vs baseline: 3.6242x; 1.1410x over previous
//
#include <hip/hip_runtime.h>
#include <math.h>

#define NPTS_C 100
#define EPS_C 1e-8

#if defined(__has_builtin)
# if __has_builtin(__builtin_amdgcn_exp2f)
#  define FAST_EXP2(x) __builtin_amdgcn_exp2f(x)
# else
#  define FAST_EXP2(x) exp2f(x)
# endif
#else
# define FAST_EXP2(x) exp2f(x)
#endif

__device__ __forceinline__ float wave_reduce_sum(float v) {
#pragma unroll
    for (int m = 1; m < 64; m <<= 1)
        v += __shfl_xor(v, m, 64);
    return v;
}

__device__ __forceinline__ float dot4(float4 a, float4 b) {
    return a.x * b.x + a.y * b.y + a.z * b.z + a.w * b.w;
}

__device__ __forceinline__ float seg_sum(const float* __restrict__ lg2,
                                         const float* __restrict__ l1g2,
                                         int base, int n,
                                         float am1, float bm1, float M2)
{
    float s0 = 0.f, s1 = 0.f;
    int p = 0;
    for (; p + 1 < n; p += 2) {
        s0 += FAST_EXP2(fmaf(am1, lg2[base + p],     fmaf(bm1, l1g2[base + p],     -M2)));
        s1 += FAST_EXP2(fmaf(am1, lg2[base + p + 1], fmaf(bm1, l1g2[base + p + 1], -M2)));
    }
    if (p < n)
        s0 += FAST_EXP2(fmaf(am1, lg2[base + p], fmaf(bm1, l1g2[base + p], -M2)));
    return s0 + s1;
}

// ---------------- Fused kernel, specialized C==512 --------------------------
// Block = 256 threads owns 64 consecutive rows. Phase 1: each wave computes
// dots for 16 rows in batches of 4 (8 float4 x-loads in flight, weights in
// registers). Phase 2: threads 0..63 each run the quadrature for one row
// (broadcast LDS table reads, hw exp2, no lgamma — mode-stabilizer cancels
// in the normalization).
__global__ __launch_bounds__(256, 4) void fused512_kernel(
    const float* __restrict__ x, const float* __restrict__ Wa,
    const float* __restrict__ ba, const float* __restrict__ Wb,
    const float* __restrict__ bb, float* __restrict__ out,
    int B, int K)
{
    __shared__ __align__(16) float s_lg2[600];
    __shared__ __align__(16) float s_l1g2[600];
    __shared__ float s_ab[64][2];

    const int tid = threadIdx.x;

    // --- row-invariant log2 tables, fp32 (matches ref's float32 grid; the
    // last point of the last segment rounds to 1.0f -> log2f(0) = -inf -> 0).
    {
        int base = 0;
        for (int i = 1; i <= K; ++i) {
            const int n = (int)((double)NPTS_C * ((double)i / (double)K));
            const double start = EPS_C;
            const double stop  = (double)i / (double)K - EPS_C;
            const double step  = (n > 1) ? (stop - start) / (double)(n - 1) : 0.0;
            for (int j = tid; j < n; j += blockDim.x) {
                const double g = (j == n - 1) ? stop : start + step * (double)j;
                const float g32 = (float)g;
                s_lg2[base + j]  = log2f(g32);
                s_l1g2[base + j] = log2f(1.0f - g32);
            }
            base += n;
        }
    }

    const int lane = tid & 63;
    const int wv   = tid >> 6;
    const float ba0 = ba[0], bb0 = bb[0];

    // --- Phase 1: GEMV, 16 rows per wave, batches of 4 ---
    {
        const float4 wa0 = *reinterpret_cast<const float4*>(Wa + 4 * lane);
        const float4 wa1 = *reinterpret_cast<const float4*>(Wa + 4 * lane + 256);
        const float4 wb0 = *reinterpret_cast<const float4*>(Wb + 4 * lane);
        const float4 wb1 = *reinterpret_cast<const float4*>(Wb + 4 * lane + 256);

        const int wrow0 = blockIdx.x * 64 + wv * 16;   // first row of this wave
        for (int r0 = 0; r0 < 16; r0 += 4) {
            const int row = wrow0 + r0;
            const float* p = x + (size_t)row * 512 + 4 * lane;
            // 8 independent loads (4 rows x 2 halves) — deep MLP
            const float4 x00 = *reinterpret_cast<const float4*>(p);
            const float4 x01 = *reinterpret_cast<const float4*>(p + 256);
            const float4 x10 = *reinterpret_cast<const float4*>(p + 512);
            const float4 x11 = *reinterpret_cast<const float4*>(p + 768);
            const float4 x20 = *reinterpret_cast<const float4*>(p + 1024);
            const float4 x21 = *reinterpret_cast<const float4*>(p + 1280);
            const float4 x30 = *reinterpret_cast<const float4*>(p + 1536);
            const float4 x31 = *reinterpret_cast<const float4*>(p + 1792);

            float da0 = dot4(x00, wa0) + dot4(x01, wa1);
            float db0 = dot4(x00, wb0) + dot4(x01, wb1);
            float da1 = dot4(x10, wa0) + dot4(x11, wa1);
            float db1 = dot4(x10, wb0) + dot4(x11, wb1);
            float da2 = dot4(x20, wa0) + dot4(x21, wa1);
            float db2 = dot4(x20, wb0) + dot4(x21, wb1);
            float da3 = dot4(x30, wa0) + dot4(x31, wa1);
            float db3 = dot4(x30, wb0) + dot4(x31, wb1);

            da0 = wave_reduce_sum(da0); db0 = wave_reduce_sum(db0);
            da1 = wave_reduce_sum(da1); db1 = wave_reduce_sum(db1);
            da2 = wave_reduce_sum(da2); db2 = wave_reduce_sum(db2);
            da3 = wave_reduce_sum(da3); db3 = wave_reduce_sum(db3);

            if (lane == 0) {
                const int lr = wv * 16 + r0;
                s_ab[lr + 0][0] = da0 + ba0; s_ab[lr + 0][1] = db0 + bb0;
                s_ab[lr + 1][0] = da1 + ba0; s_ab[lr + 1][1] = db1 + bb0;
                s_ab[lr + 2][0] = da2 + ba0; s_ab[lr + 2][1] = db2 + bb0;
                s_ab[lr + 3][0] = da3 + ba0; s_ab[lr + 3][1] = db3 + bb0;
            }
        }
    }
    __syncthreads();

    // --- Phase 2: quadrature, one thread per row (threads 0..63) ---
    if (tid < 64) {
        const int r = blockIdx.x * 64 + tid;
        if (r < B) {
            const float da = s_ab[tid][0], db = s_ab[tid][1];
            const float sa = fmaxf(da, 0.f) + log1pf(expf(-fabsf(da)));
            const float sb = fmaxf(db, 0.f) + log1pf(expf(-fabsf(db)));
            const float alpha = fminf(fmaxf(1.f + sa, 1.f), 100.f);
            const float beta  = fminf(fmaxf(1.f + sb, 1.f), 100.f);
            const float am1 = alpha - 1.f, bm1 = beta - 1.f;

            // stabilizer at the beta mode (cancels in normalization)
            const float den = am1 + bm1;
            float m = (den > 0.f) ? am1 / den : 0.5f;
            m = fminf(fmaxf(m, 1e-6f), 1.f - 1e-6f);
            const float M2 = am1 * log2f(m) + bm1 * log2f(1.f - m);

            // total = cdf_K (telescoping)
            int baseK = 0;
            for (int i = 1; i < K; ++i)
                baseK += (int)((double)NPTS_C * ((double)i / (double)K));
            const int nK = NPTS_C;
            const float total = seg_sum(s_lg2, s_l1g2, baseK, nK, am1, bm1, M2);
            const float inv_total = 1.f / total;

            float cdf_prev = 0.f;
            int base = 0;
            float* orow = out + (size_t)r * K;
            for (int i = 1; i <= K; ++i) {
                const int n = (int)((double)NPTS_C * ((double)i / (double)K));
                const float s = seg_sum(s_lg2, s_l1g2, base, n, am1, bm1, M2);
                orow[i - 1] = (s - cdf_prev) * inv_total;
                cdf_prev = s;
                base += n;
            }
        }
    }
}

// ---------------- Fallback: round-1 fused kernel (passed) ------------------
__global__ __launch_bounds__(256, 4) void ub_fused_kernel(
    const float* __restrict__ x, const float* __restrict__ Wa,
    const float* __restrict__ ba, const float* __restrict__ Wb,
    const float* __restrict__ bb, float* __restrict__ out,
    int B, int C, int K)
{
    __shared__ __align__(16) float s_lg[600];
    __shared__ __align__(16) float s_l1g[600];
    __shared__ __align__(16) float s_w[1024];

    const int tid = threadIdx.x;
    for (int c = tid; c < C; c += blockDim.x) {
        s_w[c]     = Wa[c];
        s_w[C + c] = Wb[c];
    }
    {
        int base = 0;
        for (int i = 1; i <= K; ++i) {
            const int n = (int)((double)NPTS_C * ((double)i / (double)K));
            const double start = EPS_C;
            const double stop  = (double)i / (double)K - EPS_C;
            const double step  = (n > 1) ? (stop - start) / (double)(n - 1) : 0.0;
            for (int j = tid; j < n; j += blockDim.x) {
                float g = (j == n - 1) ? (float)stop : (float)(start + step * (double)j);
                s_lg[base + j]  = logf(g);
                s_l1g[base + j] = log1pf(-g);
            }
            base += n;
        }
    }
    __syncthreads();

    const float ba0 = ba[0], bb0 = bb[0];
    const int wave = tid >> 6;
    const int lane = tid & 63;
    const int wavesPerBlock = blockDim.x >> 6;
    const int waveId = blockIdx.x * wavesPerBlock + wave;
    const int nWaves = gridDim.x * wavesPerBlock;

    for (int row = waveId; row < B; row += nWaves) {
        const float* xr = x + (size_t)row * C;
        float da = 0.f, db = 0.f;
        for (int c0 = 0; c0 < C; c0 += 256) {
            const float4 xv = *reinterpret_cast<const float4*>(xr + c0 + 4 * lane);
            const float4 wa = *reinterpret_cast<const float4*>(&s_w[c0 + 4 * lane]);
            const float4 wb = *reinterpret_cast<const float4*>(&s_w[C + c0 + 4 * lane]);
            da += xv.x * wa.x + xv.y * wa.y + xv.z * wa.z + xv.w * wa.w;
            db += xv.x * wb.x + xv.y * wb.y + xv.z * wb.z + xv.w * wb.w;
        }
        da = wave_reduce_sum(da) + ba0;
        db = wave_reduce_sum(db) + bb0;

        const float sa = fmaxf(da, 0.f) + log1pf(expf(-fabsf(da)));
        const float sb = fmaxf(db, 0.f) + log1pf(expf(-fabsf(db)));
        const float alpha = fminf(fmaxf(1.f + sa, 1.f), 100.f);
        const float beta  = fminf(fmaxf(1.f + sb, 1.f), 100.f);
        const float log_norm = lgammaf(alpha) + lgammaf(beta) - lgammaf(alpha + beta);
        const float am1 = alpha - 1.f, bm1 = beta - 1.f;

        float cdf_prev = 0.f, myp = 0.f;
        int base = 0;
        for (int i = 1; i <= K; ++i) {
            const int n = (int)((double)NPTS_C * ((double)i / (double)K));
            float s = 0.f;
            for (int p = lane; p < n; p += 64) {
                const float lp = fmaf(am1, s_lg[base + p],
                                 fmaf(bm1, s_l1g[base + p], -log_norm));
                s += expf(lp);
            }
            const float cdf = wave_reduce_sum(s);
            if (lane == i - 1) myp = cdf - cdf_prev;
            cdf_prev = cdf;
            base += n;
        }
        if (lane < K)
            out[(size_t)row * K + lane] = myp / cdf_prev;
    }
}

extern "C" void kernel_launch(void* const* d_in, const int* in_sizes, int n_in,
                              void* d_out, int out_size, void* d_ws, size_t ws_size,
                              hipStream_t stream) {
    const float* x  = (const float*)d_in[0];
    const float* Wa = (const float*)d_in[1];
    const float* ba = (const float*)d_in[2];
    const float* Wb = (const float*)d_in[3];
    const float* bb = (const float*)d_in[4];
    float* out = (float*)d_out;

    const int C = in_sizes[1];           // 512
    const int B = in_sizes[0] / C;       // 65536
    const int K = out_size / B;          // 10

    int NP = 0;
    for (int i = 1; i <= K; ++i)
        NP += (int)((double)NPTS_C * ((double)i / (double)K));

    const bool fast_ok = (C == 512) && (B % 64 == 0) && (NP <= 600);

    if (fast_ok) {
        fused512_kernel<<<B / 64, 256, 0, stream>>>(x, Wa, ba, Wb, bb, out, B, K);
    } else {
        int nblocks = (B + 3) / 4;
        if (nblocks > 2048) nblocks = 2048;
        ub_fused_kernel<<<nblocks, 256, 0, stream>>>(x, Wa, ba, Wb, bb, out, B, C, K);
    }
}

// Round 5
// 39.929 us; speedup vs baseline: 3.7420x; 1.0325x over previous
//
#include <hip/hip_runtime.h>
#include <math.h>

#define NPTS_C 100
#define EPS_C 1e-8

#if defined(__has_builtin)
# if __has_builtin(__builtin_amdgcn_exp2f)
#  define FAST_EXP2(x) __builtin_amdgcn_exp2f(x)
# else
#  define FAST_EXP2(x) exp2f(x)
# endif
#else
# define FAST_EXP2(x) exp2f(x)
#endif

__device__ __forceinline__ float wave_reduce_sum(float v) {
#pragma unroll
    for (int m = 1; m < 64; m <<= 1)
        v += __shfl_xor(v, m, 64);
    return v;
}

__device__ __forceinline__ float dot4(float4 a, float4 b) {
    return a.x * b.x + a.y * b.y + a.z * b.z + a.w * b.w;
}

// ---------------- fast path constants (C=512, K=10, NPTS=100) --------------
constexpr int KC   = 10;
constexpr int NTAB = 550;   // sum_{i=1..10} 10*i

// Block = 256 threads = 4 independent waves; each wave owns 16 consecutive
// rows end-to-end (GEMV dots + quadrature). No inter-phase barrier.
__global__ __launch_bounds__(256, 2) void fused512_kernel(
    const float* __restrict__ x, const float* __restrict__ Wa,
    const float* __restrict__ ba, const float* __restrict__ Wb,
    const float* __restrict__ bb, float* __restrict__ out)
{
    __shared__ __align__(16) float2 s_tab[NTAB];  // (log2 g, log2(1-g)), fp32 grid
    __shared__ float2 s_ab[64];                   // per-row (da, db), wave-private slices

    const int tid = threadIdx.x;

    // ---- row-invariant log2 tables (fp32 grid, matches ref; last point of
    // last segment rounds to 1.0f -> log2f(0) = -inf -> exp2 -> 0) ----
    {
        int base = 0;
#pragma unroll
        for (int i = 1; i <= KC; ++i) {
            const int n = 10 * i;
            const double start = EPS_C;
            const double stop  = (double)i / (double)KC - EPS_C;
            const double step  = (stop - start) / (double)(n - 1);
            for (int j = tid; j < n; j += 256) {
                const double g = (j == n - 1) ? stop : start + step * (double)j;
                const float g32 = (float)g;
                s_tab[base + j] = make_float2(log2f(g32), log2f(1.0f - g32));
            }
            base += n;
        }
    }
    __syncthreads();

    const int lane = tid & 63;
    const int wv   = tid >> 6;
    const float ba0 = ba[0], bb0 = bb[0];

    // ---- phase 1: dots for this wave's 16 rows; all 32 KB of loads issued
    // up-front for max memory-level parallelism ----
    const float4 wa0 = *reinterpret_cast<const float4*>(Wa + 4 * lane);
    const float4 wa1 = *reinterpret_cast<const float4*>(Wa + 4 * lane + 256);
    const float4 wb0 = *reinterpret_cast<const float4*>(Wb + 4 * lane);
    const float4 wb1 = *reinterpret_cast<const float4*>(Wb + 4 * lane + 256);

    const int rowW = blockIdx.x * 64 + wv * 16;
    const float* px = x + (size_t)rowW * 512 + 4 * lane;

#define LDX(r, h) (*reinterpret_cast<const float4*>(px + (size_t)(r) * 512 + (h) * 256))
    float4 a00=LDX(0,0),  a01=LDX(0,1),  a10=LDX(1,0),  a11=LDX(1,1);
    float4 a20=LDX(2,0),  a21=LDX(2,1),  a30=LDX(3,0),  a31=LDX(3,1);
    float4 a40=LDX(4,0),  a41=LDX(4,1),  a50=LDX(5,0),  a51=LDX(5,1);
    float4 a60=LDX(6,0),  a61=LDX(6,1),  a70=LDX(7,0),  a71=LDX(7,1);
    float4 b00=LDX(8,0),  b01=LDX(8,1),  b10=LDX(9,0),  b11=LDX(9,1);
    float4 b20=LDX(10,0), b21=LDX(10,1), b30=LDX(11,0), b31=LDX(11,1);
    float4 b40=LDX(12,0), b41=LDX(12,1), b50=LDX(13,0), b51=LDX(13,1);
    float4 b60=LDX(14,0), b61=LDX(14,1), b70=LDX(15,0), b71=LDX(15,1);
#undef LDX

#define ROWDOT(i, X0, X1) { \
    float da_ = dot4(X0, wa0) + dot4(X1, wa1); \
    float db_ = dot4(X0, wb0) + dot4(X1, wb1); \
    da_ = wave_reduce_sum(da_); db_ = wave_reduce_sum(db_); \
    if (lane == 0) s_ab[wv * 16 + (i)] = make_float2(da_ + ba0, db_ + bb0); }

    ROWDOT(0,  a00, a01) ROWDOT(1,  a10, a11) ROWDOT(2,  a20, a21) ROWDOT(3,  a30, a31)
    ROWDOT(4,  a40, a41) ROWDOT(5,  a50, a51) ROWDOT(6,  a60, a61) ROWDOT(7,  a70, a71)
    ROWDOT(8,  b00, b01) ROWDOT(9,  b10, b11) ROWDOT(10, b20, b21) ROWDOT(11, b30, b31)
    ROWDOT(12, b40, b41) ROWDOT(13, b50, b51) ROWDOT(14, b60, b61) ROWDOT(15, b70, b71)
#undef ROWDOT

    // ---- phase 2: quadrature, 4 lanes per row (points strided by 4).
    // Same-wave LDS RAW: lgkmcnt ordering suffices, no barrier. ----
    const int rowL = lane >> 2;   // 0..15: which of the wave's rows
    const int part = lane & 3;    // 0..3:  which quarter of the points

    const float2 ab = s_ab[wv * 16 + rowL];
    const float da = ab.x, db = ab.y;
    const float sa = fmaxf(da, 0.f) + log1pf(expf(-fabsf(da)));
    const float sb = fmaxf(db, 0.f) + log1pf(expf(-fabsf(db)));
    const float alpha = fminf(fmaxf(1.f + sa, 1.f), 100.f);
    const float beta  = fminf(fmaxf(1.f + sb, 1.f), 100.f);
    const float am1 = alpha - 1.f, bm1 = beta - 1.f;

    // stabilizer at the beta mode (cancels in normalization; avoids underflow)
    const float den = am1 + bm1;
    float m = (den > 0.f) ? am1 / den : 0.5f;
    m = fminf(fmaxf(m, 1e-6f), 1.f - 1e-6f);
    const float M2 = am1 * log2f(m) + bm1 * log2f(1.f - m);

    float seg[KC];
    {
        int base = 0;
#pragma unroll
        for (int i = 1; i <= KC; ++i) {
            const int n = 10 * i;
            float s = 0.f;
            for (int t = part; t < n; t += 4) {
                const float2 e = s_tab[base + t];
                s += FAST_EXP2(fmaf(am1, e.x, fmaf(bm1, e.y, -M2)));
            }
            seg[i - 1] = s;
            base += n;
        }
    }
    // combine the 4 quarter-partials within each 4-lane group
#pragma unroll
    for (int i = 0; i < KC; ++i) {
        seg[i] += __shfl_xor(seg[i], 1, 64);
        seg[i] += __shfl_xor(seg[i], 2, 64);
    }

    if (part == 0) {
        float* orow = out + (size_t)(rowW + rowL) * KC;
        const float inv_total = 1.f / seg[KC - 1];   // total = cdf_K (telescoping)
        float prev = 0.f;
#pragma unroll
        for (int j = 0; j < KC; ++j) {
            orow[j] = (seg[j] - prev) * inv_total;
            prev = seg[j];
        }
    }
}

// ---------------- Fallback: round-1 fused kernel (passed) ------------------
__global__ __launch_bounds__(256, 4) void ub_fused_kernel(
    const float* __restrict__ x, const float* __restrict__ Wa,
    const float* __restrict__ ba, const float* __restrict__ Wb,
    const float* __restrict__ bb, float* __restrict__ out,
    int B, int C, int K)
{
    __shared__ __align__(16) float s_lg[600];
    __shared__ __align__(16) float s_l1g[600];
    __shared__ __align__(16) float s_w[1024];

    const int tid = threadIdx.x;
    for (int c = tid; c < C; c += blockDim.x) {
        s_w[c]     = Wa[c];
        s_w[C + c] = Wb[c];
    }
    {
        int base = 0;
        for (int i = 1; i <= K; ++i) {
            const int n = (int)((double)NPTS_C * ((double)i / (double)K));
            const double start = EPS_C;
            const double stop  = (double)i / (double)K - EPS_C;
            const double step  = (n > 1) ? (stop - start) / (double)(n - 1) : 0.0;
            for (int j = tid; j < n; j += blockDim.x) {
                float g = (j == n - 1) ? (float)stop : (float)(start + step * (double)j);
                s_lg[base + j]  = logf(g);
                s_l1g[base + j] = log1pf(-g);
            }
            base += n;
        }
    }
    __syncthreads();

    const float ba0 = ba[0], bb0 = bb[0];
    const int wave = tid >> 6;
    const int lane = tid & 63;
    const int wavesPerBlock = blockDim.x >> 6;
    const int waveId = blockIdx.x * wavesPerBlock + wave;
    const int nWaves = gridDim.x * wavesPerBlock;

    for (int row = waveId; row < B; row += nWaves) {
        const float* xr = x + (size_t)row * C;
        float da = 0.f, db = 0.f;
        for (int c0 = 0; c0 < C; c0 += 256) {
            const float4 xv = *reinterpret_cast<const float4*>(xr + c0 + 4 * lane);
            const float4 wa = *reinterpret_cast<const float4*>(&s_w[c0 + 4 * lane]);
            const float4 wb = *reinterpret_cast<const float4*>(&s_w[C + c0 + 4 * lane]);
            da += xv.x * wa.x + xv.y * wa.y + xv.z * wa.z + xv.w * wa.w;
            db += xv.x * wb.x + xv.y * wb.y + xv.z * wb.z + xv.w * wb.w;
        }
        da = wave_reduce_sum(da) + ba0;
        db = wave_reduce_sum(db) + bb0;

        const float sa = fmaxf(da, 0.f) + log1pf(expf(-fabsf(da)));
        const float sb = fmaxf(db, 0.f) + log1pf(expf(-fabsf(db)));
        const float alpha = fminf(fmaxf(1.f + sa, 1.f), 100.f);
        const float beta  = fminf(fmaxf(1.f + sb, 1.f), 100.f);
        const float log_norm = lgammaf(alpha) + lgammaf(beta) - lgammaf(alpha + beta);
        const float am1 = alpha - 1.f, bm1 = beta - 1.f;

        float cdf_prev = 0.f, myp = 0.f;
        int base = 0;
        for (int i = 1; i <= K; ++i) {
            const int n = (int)((double)NPTS_C * ((double)i / (double)K));
            float s = 0.f;
            for (int p = lane; p < n; p += 64) {
                const float lp = fmaf(am1, s_lg[base + p],
                                 fmaf(bm1, s_l1g[base + p], -log_norm));
                s += expf(lp);
            }
            const float cdf = wave_reduce_sum(s);
            if (lane == i - 1) myp = cdf - cdf_prev;
            cdf_prev = cdf;
            base += n;
        }
        if (lane < K)
            out[(size_t)row * K + lane] = myp / cdf_prev;
    }
}

extern "C" void kernel_launch(void* const* d_in, const int* in_sizes, int n_in,
                              void* d_out, int out_size, void* d_ws, size_t ws_size,
                              hipStream_t stream) {
    const float* x  = (const float*)d_in[0];
    const float* Wa = (const float*)d_in[1];
    const float* ba = (const float*)d_in[2];
    const float* Wb = (const float*)d_in[3];
    const float* bb = (const float*)d_in[4];
    float* out = (float*)d_out;

    const int C = in_sizes[1];           // 512
    const int B = in_sizes[0] / C;       // 65536
    const int K = out_size / B;          // 10

    const bool fast_ok = (C == 512) && (K == 10) && (B % 64 == 0);

    if (fast_ok) {
        fused512_kernel<<<B / 64, 256, 0, stream>>>(x, Wa, ba, Wb, bb, out);
    } else {
        int nblocks = (B + 3) / 4;
        if (nblocks > 2048) nblocks = 2048;
        ub_fused_kernel<<<nblocks, 256, 0, stream>>>(x, Wa, ba, Wb, bb, out, B, C, K);
    }
}

// Round 7
// 32.359 us; speedup vs baseline: 4.6174x; 1.2339x over previous
//
#include <hip/hip_runtime.h>
#include <math.h>

#define NPTS_C 100
#define EPS_C 1e-8

#if defined(__has_builtin)
# if __has_builtin(__builtin_amdgcn_exp2f)
#  define FAST_EXP2(x) __builtin_amdgcn_exp2f(x)
# else
#  define FAST_EXP2(x) exp2f(x)
# endif
#else
# define FAST_EXP2(x) exp2f(x)
#endif

__device__ __forceinline__ float dot4(float4 a, float4 b) {
    return a.x * b.x + a.y * b.y + a.z * b.z + a.w * b.w;
}

__device__ __forceinline__ float wave_reduce_sum(float v) {
#pragma unroll
    for (int m = 1; m < 64; m <<= 1)
        v += __shfl_xor(v, m, 64);
    return v;
}

// ---------------- fast path constants (C=512, K=10, NPTS=100) --------------
constexpr int KC   = 10;
constexpr int NTAB = 550;   // sum_{i=1..10} 10*i

// Block = 256 threads = 4 waves; each wave owns 8 rows.
// Layout: row = lane&7, part = lane>>3 (8 lanes per row).
//  - x loads: per instruction the wave covers 8 rows x 128 contiguous bytes
//    (fully-used cache lines). Lane's slice j is float4 #(part + 8*j) of the
//    row, i.e. float offset part*4 + j*32.
//  - row-dot reduction for ALL 8 rows = 3 butterfly steps (xor 8/16/32).
//  - quadrature: 8 lanes per row, ~69 points/lane, 3-step combine; result
//    already resident in the right lanes (no LDS round-trip).
__global__ __launch_bounds__(256, 3) void fused512_kernel(
    const float* __restrict__ x, const float* __restrict__ Wa,
    const float* __restrict__ ba, const float* __restrict__ Wb,
    const float* __restrict__ bb, float* __restrict__ out)
{
    __shared__ __align__(16) float2 s_tab[NTAB];   // (log2 g, log2(1-g)), fp32 grid
    __shared__ __align__(16) float4 s_w4[256];     // [0..127] Wa, [128..255] Wb

    const int tid = threadIdx.x;

    // ---- stage weights as float4 ----
    if (tid < 128) {
        s_w4[tid]       = reinterpret_cast<const float4*>(Wa)[tid];
        s_w4[128 + tid] = reinterpret_cast<const float4*>(Wb)[tid];
    }

    // ---- row-invariant log2 tables (fp32 grid, matches ref; last point of
    // last segment rounds to 1.0f -> log2f(0) = -inf -> exp2 -> 0) ----
    {
        int base = 0;
#pragma unroll
        for (int i = 1; i <= KC; ++i) {
            const int n = 10 * i;
            const double start = EPS_C;
            const double stop  = (double)i / (double)KC - EPS_C;
            const double step  = (stop - start) / (double)(n - 1);
            for (int j = tid; j < n; j += 256) {
                const double g = (j == n - 1) ? stop : start + step * (double)j;
                const float g32 = (float)g;
                s_tab[base + j] = make_float2(log2f(g32), log2f(1.0f - g32));
            }
            base += n;
        }
    }
    __syncthreads();

    const int lane = tid & 63;
    const int wv   = tid >> 6;
    const int r8   = lane & 7;    // which of the wave's 8 rows
    const int part = lane >> 3;   // 0..7: this lane's slice of the row
    const float ba0 = ba[0], bb0 = bb[0];

    const int row = blockIdx.x * 32 + wv * 8 + r8;
    const float* px = x + (size_t)row * 512 + part * 4;

    // ---- phase 1: load this lane's 16 float4 slices (16 KB/wave in flight)
    float4 xv[16];
#pragma unroll
    for (int j = 0; j < 16; ++j)
        xv[j] = *reinterpret_cast<const float4*>(px + (size_t)j * 32);  // 32 floats = 128 B

    float da = 0.f, db = 0.f;
#pragma unroll
    for (int j = 0; j < 16; ++j) {
        const float4 wa = s_w4[part + 8 * j];
        const float4 wb = s_w4[128 + part + 8 * j];
        da += dot4(xv[j], wa);
        db += dot4(xv[j], wb);
    }
    // reduce across the 8 lanes holding this row (all 8 rows at once)
    da += __shfl_xor(da, 8, 64);  db += __shfl_xor(db, 8, 64);
    da += __shfl_xor(da, 16, 64); db += __shfl_xor(db, 16, 64);
    da += __shfl_xor(da, 32, 64); db += __shfl_xor(db, 32, 64);
    da += ba0; db += bb0;

    // ---- per-row scalars (8-way redundant; cheaper than communicating) ----
    const float sa = fmaxf(da, 0.f) + log1pf(expf(-fabsf(da)));
    const float sb = fmaxf(db, 0.f) + log1pf(expf(-fabsf(db)));
    const float alpha = fminf(fmaxf(1.f + sa, 1.f), 100.f);
    const float beta  = fminf(fmaxf(1.f + sb, 1.f), 100.f);
    const float am1 = alpha - 1.f, bm1 = beta - 1.f;

    // stabilizer at the beta mode (cancels in normalization; avoids underflow)
    const float den = am1 + bm1;
    float m = (den > 0.f) ? am1 / den : 0.5f;
    m = fminf(fmaxf(m, 1e-6f), 1.f - 1e-6f);
    const float M2 = am1 * log2f(m) + bm1 * log2f(1.f - m);

    // ---- phase 2: quadrature, 8 lanes per row, points strided by 8 ----
    float seg[KC];
    {
        int base = 0;
#pragma unroll
        for (int i = 1; i <= KC; ++i) {
            const int n = 10 * i;
            float s = 0.f;
            for (int t = part; t < n; t += 8) {
                const float2 e = s_tab[base + t];
                s += FAST_EXP2(fmaf(am1, e.x, fmaf(bm1, e.y, -M2)));
            }
            seg[i - 1] = s;
            base += n;
        }
    }
#pragma unroll
    for (int i = 0; i < KC; ++i) {
        seg[i] += __shfl_xor(seg[i], 8, 64);
        seg[i] += __shfl_xor(seg[i], 16, 64);
        seg[i] += __shfl_xor(seg[i], 32, 64);
    }

    if (part == 0) {
        float* orow = out + (size_t)row * KC;
        const float inv_total = 1.f / seg[KC - 1];   // total = cdf_K (telescoping)
        float prev = 0.f;
        float2* o2 = reinterpret_cast<float2*>(orow);  // 40B rows are 8B-aligned
#pragma unroll
        for (int j = 0; j < KC; j += 2) {
            const float p0 = (seg[j]     - prev)   * inv_total;
            const float p1 = (seg[j + 1] - seg[j]) * inv_total;
            o2[j >> 1] = make_float2(p0, p1);
            prev = seg[j + 1];
        }
    }
}

// ---------------- Fallback: round-1 fused kernel (passed) ------------------
__global__ __launch_bounds__(256, 4) void ub_fused_kernel(
    const float* __restrict__ x, const float* __restrict__ Wa,
    const float* __restrict__ ba, const float* __restrict__ Wb,
    const float* __restrict__ bb, float* __restrict__ out,
    int B, int C, int K)
{
    __shared__ __align__(16) float s_lg[600];
    __shared__ __align__(16) float s_l1g[600];
    __shared__ __align__(16) float s_w[1024];

    const int tid = threadIdx.x;
    for (int c = tid; c < C; c += blockDim.x) {
        s_w[c]     = Wa[c];
        s_w[C + c] = Wb[c];
    }
    {
        int base = 0;
        for (int i = 1; i <= K; ++i) {
            const int n = (int)((double)NPTS_C * ((double)i / (double)K));
            const double start = EPS_C;
            const double stop  = (double)i / (double)K - EPS_C;
            const double step  = (n > 1) ? (stop - start) / (double)(n - 1) : 0.0;
            for (int j = tid; j < n; j += blockDim.x) {
                float g = (j == n - 1) ? (float)stop : (float)(start + step * (double)j);
                s_lg[base + j]  = logf(g);
                s_l1g[base + j] = log1pf(-g);
            }
            base += n;
        }
    }
    __syncthreads();

    const float ba0 = ba[0], bb0 = bb[0];
    const int wave = tid >> 6;
    const int lane = tid & 63;
    const int wavesPerBlock = blockDim.x >> 6;
    const int waveId = blockIdx.x * wavesPerBlock + wave;
    const int nWaves = gridDim.x * wavesPerBlock;

    for (int row = waveId; row < B; row += nWaves) {
        const float* xr = x + (size_t)row * C;
        float da = 0.f, db = 0.f;
        for (int c0 = 0; c0 < C; c0 += 256) {
            const float4 xv = *reinterpret_cast<const float4*>(xr + c0 + 4 * lane);
            const float4 wa = *reinterpret_cast<const float4*>(&s_w[c0 + 4 * lane]);
            const float4 wb = *reinterpret_cast<const float4*>(&s_w[C + c0 + 4 * lane]);
            da += xv.x * wa.x + xv.y * wa.y + xv.z * wa.z + xv.w * wa.w;
            db += xv.x * wb.x + xv.y * wb.y + xv.z * wb.z + xv.w * wb.w;
        }
        da = wave_reduce_sum(da) + ba0;
        db = wave_reduce_sum(db) + bb0;

        const float sa = fmaxf(da, 0.f) + log1pf(expf(-fabsf(da)));
        const float sb = fmaxf(db, 0.f) + log1pf(expf(-fabsf(db)));
        const float alpha = fminf(fmaxf(1.f + sa, 1.f), 100.f);
        const float beta  = fminf(fmaxf(1.f + sb, 1.f), 100.f);
        const float log_norm = lgammaf(alpha) + lgammaf(beta) - lgammaf(alpha + beta);
        const float am1 = alpha - 1.f, bm1 = beta - 1.f;

        float cdf_prev = 0.f, myp = 0.f;
        int base = 0;
        for (int i = 1; i <= K; ++i) {
            const int n = (int)((double)NPTS_C * ((double)i / (double)K));
            float s = 0.f;
            for (int p = lane; p < n; p += 64) {
                const float lp = fmaf(am1, s_lg[base + p],
                                 fmaf(bm1, s_l1g[base + p], -log_norm));
                s += expf(lp);
            }
            const float cdf = wave_reduce_sum(s);
            if (lane == i - 1) myp = cdf - cdf_prev;
            cdf_prev = cdf;
            base += n;
        }
        if (lane < K)
            out[(size_t)row * K + lane] = myp / cdf_prev;
    }
}

extern "C" void kernel_launch(void* const* d_in, const int* in_sizes, int n_in,
                              void* d_out, int out_size, void* d_ws, size_t ws_size,
                              hipStream_t stream) {
    const float* x  = (const float*)d_in[0];
    const float* Wa = (const float*)d_in[1];
    const float* ba = (const float*)d_in[2];
    const float* Wb = (const float*)d_in[3];
    const float* bb = (const float*)d_in[4];
    float* out = (float*)d_out;

    const int C = in_sizes[1];           // 512
    const int B = in_sizes[0] / C;       // 65536
    const int K = out_size / B;          // 10

    const bool fast_ok = (C == 512) && (K == 10) && (B % 32 == 0);

    if (fast_ok) {
        fused512_kernel<<<B / 32, 256, 0, stream>>>(x, Wa, ba, Wb, bb, out);
    } else {
        int nblocks = (B + 3) / 4;
        if (nblocks > 2048) nblocks = 2048;
        ub_fused_kernel<<<nblocks, 256, 0, stream>>>(x, Wa, ba, Wb, bb, out, B, C, K);
    }
}